// Round 7
// baseline (5939.020 us; speedup 1.0000x reference)
//
#include <hip/hip_runtime.h>
#include <stdint.h>

#pragma clang fp contract(off)

#define N_PRIM   1000000
#define GRID_G   512
#define NCELLS   (GRID_G*GRID_G)          // 262144
#define FOCAL_C  768.0f
#define NP2      1048576                  // 2^20 padded count
#define SB       1024                     // sort blocks
#define EPB      1024                     // elems per sort block (256 thr * 4)
#define PREP_BLOCKS 2048                  // 512 prims per block

// ---------------- workspace layout (bytes) ----------------
#define O_SORTA  ((size_t)0)
#define O_SORTB  (O_SORTA + (size_t)NP2*8)            // 8,388,608
#define O_REC    (O_SORTB + (size_t)NP2*8)            // 16,777,216
#define O_CCNT   (O_REC   + (size_t)N_PRIM*64)        // 80,777,216  <- memset from here
#define O_CSTAT  (O_CCNT  + (size_t)NCELLS*4)         // cells-scan lookback status (4 KB)
#define O_GHIST  (O_CSTAT + 4096)                     // 4*256 u32 global hists (4 KB)
#define O_STATUS (O_GHIST + 4096)                     // scatter lookback 4*256*1024 u32 (4 MB)
#define O_ZEND   (O_STATUS + (size_t)4*256*1024*4)    // <- memset to here
#define O_GBASE  (O_ZEND)                             // scanned digit bases (4 KB)
#define O_VCNT   (O_GBASE + 4096)                     // 2048 u32 (8 KB)
#define O_COFS   (O_VCNT  + 8192)
#define O_ENTRY  (O_COFS  + (size_t)NCELLS*4)
#define WS_NEED  (O_ENTRY + (size_t)4*N_PRIM*4)       // ~103.1 MB

__device__ __forceinline__ int swz(int q) { return q ^ ((q >> 3) & 7); }

// ---------------------------------------------------------------------------
__global__ __launch_bounds__(256) void k_prep(
    const float* __restrict__ centers, const float* __restrict__ scales,
    const float* __restrict__ rotations, const float* __restrict__ colors,
    const float* __restrict__ opac, const float* __restrict__ mvp,
    uint64_t* __restrict__ sortA, float4* __restrict__ rec,
    uint32_t* __restrict__ cellcnt, uint32_t* __restrict__ vcnt)
{
  __shared__ float4 srec[2048];          // 512 prims * 4 float4 (swizzled)
  __shared__ uint32_t swcnt[4];
  int t = threadIdx.x;
  int pair = blockIdx.x*256 + t;
  int p0 = pair*2;
  bool live = p0 < N_PRIM;               // pairs never straddle N (N even)

  float m0=mvp[0], m1=mvp[1], m2=mvp[2],  m3=mvp[3];
  float m4=mvp[4], m5=mvp[5], m6=mvp[6],  m7=mvp[7];
  float m8=mvp[8], m9=mvp[9], m10=mvp[10],m11=mvp[11];

  bool valid0=false, valid1=false;
  uint64_t pk0 = ~0ULL, pk1 = ~0ULL;     // padding sorts strictly last

  if (live) {
    const float2* cp = (const float2*)(centers + (size_t)pair*6);
    float2 ca = cp[0], cb = cp[1], cc = cp[2];
    const float2* sp = (const float2*)(scales + (size_t)pair*6);
    float2 sa = sp[0], sb2 = sp[1], sc2 = sp[2];
    const float4* rp = (const float4*)rotations;
    float4 q0 = rp[p0], q1 = rp[p0+1];
    const float2* colp = (const float2*)(colors + (size_t)pair*6);
    float2 ka = colp[0], kb = colp[1], kc = colp[2];
    float2 o2 = ((const float2*)opac)[pair];

    auto doPrim = [&](int i, float c0, float c1, float c2,
                      float s0, float s1, float s2,
                      float qw, float qx, float qy, float qz,
                      float col0, float col1, float col2, float op,
                      uint64_t& pk, bool& validf, int lidx) {
      float n0 = fmaf(m2,  c2, fmaf(m1, c1, m0*c0)) + m3;
      float n1 = fmaf(m6,  c2, fmaf(m5, c1, m4*c0)) + m7;
      float n2 = fmaf(m10, c2, fmaf(m9, c1, m8*c0)) + m11;
      bool valid = n2 > 0.0f;
      validf = valid;
      float cx = (n0 + 1.0f)*0.5f;
      float cy = (n1 + 1.0f)*0.5f;
      // sort key: exact float bits of clip(z,1e-6) (monotone for positives);
      // invalid -> bits of 1e30f. Stability via stable LSD passes.
      uint32_t key32 = valid ? __float_as_uint(fmaxf(n2, 1e-6f)) : 0x7149F2CAu;
      pk = ((uint64_t)key32 << 20) | (uint32_t)i;

      float nrm = sqrtf(qw*qw + qx*qx + qy*qy + qz*qz);
      nrm = fmaxf(nrm, 1e-12f);
      qw /= nrm; qx /= nrm; qy /= nrm; qz /= nrm;
      float R00 = 1.0f - 2.0f*(qy*qy + qz*qz);
      float R01 = 2.0f*(qx*qy - qz*qw);
      float R02 = 2.0f*(qx*qz + qy*qw);
      float R10 = 2.0f*(qx*qy + qz*qw);
      float R11 = 1.0f - 2.0f*(qx*qx + qz*qz);
      float R12 = 2.0f*(qy*qz - qx*qw);
      float R20 = 2.0f*(qx*qz - qy*qw);
      float R21 = 2.0f*(qy*qz + qx*qw);
      float R22 = 1.0f - 2.0f*(qx*qx + qy*qy);
      s0 = fmaxf(s0, 1e-9f); s1 = fmaxf(s1, 1e-9f); s2 = fmaxf(s2, 1e-9f);
      float L00=R00*s0, L01=R01*s1, L02=R02*s2;
      float L10=R10*s0, L11=R11*s1, L12=R12*s2;
      float L20=R20*s0, L21=R21*s1, L22=R22*s2;
      float cv00 = fmaf(L02,L02, fmaf(L01,L01, L00*L00));
      float cv01 = fmaf(L02,L12, fmaf(L01,L11, L00*L10));
      float cv02 = fmaf(L02,L22, fmaf(L01,L21, L00*L20));
      float cv11 = fmaf(L12,L12, fmaf(L11,L11, L10*L10));
      float cv12 = fmaf(L12,L22, fmaf(L11,L21, L10*L20));
      float cv22 = fmaf(L22,L22, fmaf(L21,L21, L20*L20));
      float T00 = fmaf(m2,cv02, fmaf(m1,cv01, m0*cv00));
      float T01 = fmaf(m2,cv12, fmaf(m1,cv11, m0*cv01));
      float T02 = fmaf(m2,cv22, fmaf(m1,cv12, m0*cv02));
      float T10 = fmaf(m6,cv02, fmaf(m5,cv01, m4*cv00));
      float T11 = fmaf(m6,cv12, fmaf(m5,cv11, m4*cv01));
      float T12 = fmaf(m6,cv22, fmaf(m5,cv12, m4*cv02));
      float cc00 = fmaf(T02,m2, fmaf(T01,m1, T00*m0));
      float cc01 = fmaf(T02,m6, fmaf(T01,m5, T00*m4));
      float cc11 = fmaf(T12,m6, fmaf(T11,m5, T10*m4));
      float zc  = fmaxf(n2, 1e-6f);
      float scv = FOCAL_C / zc;
      float sc22 = scv*scv;
      float c00 = cc00*sc22, c01 = cc01*sc22, c11 = cc11*sc22;

      float rx = (3.0f * sqrtf(fmaxf(c00, 0.0f))) / 512.0f;
      float ry = (3.0f * sqrtf(fmaxf(c11, 0.0f))) / 512.0f;
      int x0 = (int)floorf((cx - rx) * 512.0f);
      int x1 = (int)floorf((cx + rx) * 512.0f);
      int y0 = (int)floorf((cy - ry) * 512.0f);
      int y1 = (int)floorf((cy + ry) * 512.0f);
      int cl[4];
      #pragma unroll
      for (int ky = 0; ky < 2; ++ky) {
        int yy = y0 + ky;
        bool vy = (yy <= y1) && (yy >= 0) && (yy < GRID_G);
        #pragma unroll
        for (int kx = 0; kx < 2; ++kx) {
          int xx = x0 + kx;
          bool vx = (xx <= x1) && (xx >= 0) && (xx < GRID_G);
          int cell = (valid && vy && vx) ? (yy*GRID_G + xx) : -1;
          cl[ky*2+kx] = cell;
          if (cell >= 0) atomicAdd(&cellcnt[cell], 1u);
        }
      }
      float opv = fminf(fmaxf(op, 0.0f), 1.0f);
      float vf = valid ? 1.0f : 0.0f;
      int lb = lidx*4;
      srec[swz(lb+0)] = make_float4(cx, cy, c00, c01);
      srec[swz(lb+1)] = make_float4(c11, col0, col1, col2);
      srec[swz(lb+2)] = make_float4(opv, vf, 0.0f, 0.0f);
      srec[swz(lb+3)] = make_float4(__int_as_float(cl[0]), __int_as_float(cl[1]),
                                    __int_as_float(cl[2]), __int_as_float(cl[3]));
    };

    doPrim(p0,   ca.x, ca.y, cb.x, sa.x, sa.y, sb2.x,
           q0.x, q0.y, q0.z, q0.w, ka.x, ka.y, kb.x, o2.x, pk0, valid0, 2*t);
    doPrim(p0+1, cb.y, cc.x, cc.y, sb2.y, sc2.x, sc2.y,
           q1.x, q1.y, q1.z, q1.w, kb.y, kc.x, kc.y, o2.y, pk1, valid1, 2*t+1);
  }

  ((ulonglong2*)sortA)[pair] = make_ulonglong2(pk0, pk1);

  unsigned long long b0 = __ballot(live && valid0);
  unsigned long long b1 = __ballot(live && valid1);
  if ((t & 63) == 0) swcnt[t >> 6] = (uint32_t)(__popcll(b0) + __popcll(b1));
  __syncthreads();
  if (t == 0) vcnt[blockIdx.x] = swcnt[0]+swcnt[1]+swcnt[2]+swcnt[3];

  // coalesced rec writeout
  size_t gbase2 = (size_t)blockIdx.x*2048;
  for (int q = t; q < 2048; q += 256) {
    size_t gi = gbase2 + q;
    if (gi < (size_t)N_PRIM*4) rec[gi] = srec[swz(q)];
  }
}

// -------- single-pass exclusive scan (decoupled lookback), 256/block --------
// status[b] packed: state(2b)<<30 | value(30b). Pre-zeroed each launch.
__global__ __launch_bounds__(256) void k_scan1(
    const uint32_t* __restrict__ in, uint32_t* __restrict__ ofs,
    uint32_t* __restrict__ status,
    const uint32_t* __restrict__ vcnt, const float* __restrict__ bg,
    float* __restrict__ out)
{
  __shared__ uint32_t s[256];
  __shared__ uint32_t sprefix;
  int t = threadIdx.x, bid = blockIdx.x;
  int i = bid*256 + t;
  uint32_t v = in[i];
  s[t] = v; __syncthreads();
  for (int o = 1; o < 256; o <<= 1) {
    uint32_t u = (t >= o) ? s[t-o] : 0u; __syncthreads();
    s[t] += u; __syncthreads();
  }
  uint32_t total = s[255];
  if (t == 0) {
    if (bid == 0) {
      __hip_atomic_store(&status[0], (2u<<30)|total, __ATOMIC_RELEASE, __HIP_MEMORY_SCOPE_AGENT);
      sprefix = 0;
    } else {
      __hip_atomic_store(&status[bid], (1u<<30)|total, __ATOMIC_RELEASE, __HIP_MEMORY_SCOPE_AGENT);
      uint32_t run = 0; int j = bid-1;
      while (true) {
        uint32_t sv = __hip_atomic_load(&status[j], __ATOMIC_ACQUIRE, __HIP_MEMORY_SCOPE_AGENT);
        uint32_t st = sv >> 30;
        if (st == 0u) continue;
        run += sv & 0x3FFFFFFFu;
        if (st == 2u) break;
        --j;
      }
      __hip_atomic_store(&status[bid], (2u<<30)|(run+total), __ATOMIC_RELEASE, __HIP_MEMORY_SCOPE_AGENT);
      sprefix = run;
    }
  }
  __syncthreads();
  ofs[i] = sprefix + s[t] - v;

  if (vcnt && bid == 0) {          // header fold-in
    __syncthreads();
    uint32_t a2 = 0;
    for (int i2 = t; i2 < PREP_BLOCKS; i2 += 256) a2 += vcnt[i2];
    s[t] = a2; __syncthreads();
    #pragma unroll
    for (int o = 128; o > 0; o >>= 1) { if (t < o) s[t] += s[t+o]; __syncthreads(); }
    if (t == 0) {
      out[0] = (float)s[0];
      out[1] = 512.0f;
      out[2] = 64.0f;
      out[3] = bg[0]; out[4] = bg[1]; out[5] = bg[2];
    }
  }
}

// -------- global 4-pass digit histogram (digit counts are perm-invariant) ---
__global__ __launch_bounds__(256) void k_ghist(const uint64_t* __restrict__ keys,
                                               uint32_t* __restrict__ ghist)
{
  __shared__ uint32_t h[1024];
  int t = threadIdx.x;
  #pragma unroll
  for (int q = 0; q < 4; ++q) h[q*256 + t] = 0;
  __syncthreads();
  const ulonglong2* k2 = (const ulonglong2*)(keys + (size_t)blockIdx.x*4096);
  #pragma unroll
  for (int j = 0; j < 8; ++j) {
    ulonglong2 w = k2[j*256 + t];
    #pragma unroll
    for (int p = 0; p < 4; ++p) {
      int sh = 20 + 8*p;
      atomicAdd(&h[p*256 + ((uint32_t)(w.x >> sh) & 255u)], 1u);
      atomicAdd(&h[p*256 + ((uint32_t)(w.y >> sh) & 255u)], 1u);
    }
  }
  __syncthreads();
  #pragma unroll
  for (int q = 0; q < 4; ++q) atomicAdd(&ghist[q*256 + t], h[q*256 + t]);
}

__global__ void k_gscan(const uint32_t* __restrict__ ghist, uint32_t* __restrict__ gbase)
{
  __shared__ uint32_t s[256];
  int t = threadIdx.x;
  for (int p = 0; p < 4; ++p) {
    uint32_t v = ghist[p*256 + t];
    s[t] = v; __syncthreads();
    for (int o = 1; o < 256; o <<= 1) {
      uint32_t u = (t >= o) ? s[t-o] : 0u; __syncthreads();
      s[t] += u; __syncthreads();
    }
    gbase[p*256 + t] = s[t] - v;
    __syncthreads();
  }
}

// -------- onesweep scatter: lookback per digit for cross-block offsets ------
__global__ __launch_bounds__(256) void k_scatter(
    const uint64_t* __restrict__ in, uint64_t* __restrict__ outp,
    const uint32_t* __restrict__ gbase, uint32_t* __restrict__ status,
    int shift)
{
  __shared__ uint32_t s_base[256];
  __shared__ uint32_t lbase[256];
  __shared__ uint32_t s_run[256];
  __shared__ uint32_t s_wcnt[1024];   // [bin][wave]
  __shared__ uint64_t stage[EPB];     // 8 KB
  int t = threadIdx.x, bid = blockIdx.x;
  int wid = t >> 6, lane = t & 63;
  lbase[t] = 0; s_run[t] = 0;
  __syncthreads();
  size_t base = (size_t)bid*EPB;
  uint64_t v[4]; uint32_t d[4];
  #pragma unroll
  for (int j = 0; j < 4; ++j) {
    v[j] = in[base + j*256 + t];
    d[j] = (uint32_t)(v[j] >> shift) & 255u;
  }
  #pragma unroll
  for (int j = 0; j < 4; ++j) atomicAdd(&lbase[d[j]], 1u);
  __syncthreads();
  uint32_t bincnt = lbase[t];
  uint32_t* st = status + (size_t)t*SB;    // status[digit][block] this pass
  if (bid == 0) {
    __hip_atomic_store(&st[0], (2u<<30)|bincnt, __ATOMIC_RELEASE, __HIP_MEMORY_SCOPE_AGENT);
    s_base[t] = gbase[t];
  } else {
    __hip_atomic_store(&st[bid], (1u<<30)|bincnt, __ATOMIC_RELEASE, __HIP_MEMORY_SCOPE_AGENT);
  }
  // in-block exclusive offsets per digit
  for (int o = 1; o < 256; o <<= 1) {
    uint32_t u = (t >= o) ? lbase[t-o] : 0u; __syncthreads();
    lbase[t] += u; __syncthreads();
  }
  uint32_t myexcl = lbase[t] - bincnt;
  __syncthreads();
  lbase[t] = myexcl;
  // per-digit lookback (thread t owns digit t)
  if (bid > 0) {
    uint32_t run = 0; int j = bid-1;
    while (true) {
      uint32_t sv = __hip_atomic_load(&st[j], __ATOMIC_ACQUIRE, __HIP_MEMORY_SCOPE_AGENT);
      uint32_t s2 = sv >> 30;
      if (s2 == 0u) continue;
      run += sv & 0x3FFFFFFFu;
      if (s2 == 2u) break;
      --j;
    }
    __hip_atomic_store(&st[bid], (2u<<30)|(run+bincnt), __ATOMIC_RELEASE, __HIP_MEMORY_SCOPE_AGENT);
    s_base[t] = gbase[t] + run;
  }
  __syncthreads();

  #pragma unroll
  for (int j = 0; j < 4; ++j) {           // wave-ordered stable ranking
    #pragma unroll
    for (int q0 = 0; q0 < 4; ++q0) s_wcnt[q0*256 + t] = 0;
    __syncthreads();
    unsigned long long m = ~0ULL;
    #pragma unroll
    for (int bit = 0; bit < 8; ++bit) {
      unsigned long long vote = __ballot((d[j] >> bit) & 1);
      m &= ((d[j] >> bit) & 1) ? vote : ~vote;
    }
    uint32_t lr = __popcll(m & ((1ULL << lane) - 1ULL));
    if (lr == 0) s_wcnt[d[j]*4 + wid] = (uint32_t)__popcll(m);
    __syncthreads();
    uint32_t wb = 0;
    #pragma unroll
    for (int w = 0; w < 3; ++w) if (w < wid) wb += s_wcnt[d[j]*4 + w];
    stage[lbase[d[j]] + s_run[d[j]] + wb + lr] = v[j];
    __syncthreads();
    s_run[t] += s_wcnt[t*4] + s_wcnt[t*4+1] + s_wcnt[t*4+2] + s_wcnt[t*4+3];
    __syncthreads();
  }
  // block-sorted stage -> coalesced global writes
  #pragma unroll
  for (int j = 0; j < 4; ++j) {
    int q = j*256 + t;
    uint64_t sv = stage[q];
    uint32_t sd = (uint32_t)(sv >> shift) & 255u;
    outp[s_base[sd] + ((uint32_t)q - lbase[sd])] = sv;
  }
}

// ---------------- result rows (direct stores) + entry emit ------------------
__global__ __launch_bounds__(256) void k_result(
    const uint64_t* __restrict__ sorted, const float4* __restrict__ rec,
    uint32_t* __restrict__ cursor, uint32_t* __restrict__ entry,
    float* __restrict__ out)
{
  int i = blockIdx.x*256 + threadIdx.x;
  if (i >= N_PRIM) return;
  uint64_t v = sorted[i];
  int o = (int)(v & 0xFFFFFu);
  float4 a = rec[(size_t)o*4],   b = rec[(size_t)o*4+1];
  float4 c = rec[(size_t)o*4+2], dd = rec[(size_t)o*4+3];
  float vf = c.y;
  float2* w = (float2*)(out + 6 + (size_t)i*20);
  w[0] = make_float2(5.0f*vf, a.x*vf);
  w[1] = make_float2(a.y*vf, a.z*vf);
  w[2] = make_float2(a.w*vf, b.x*vf);
  w[3] = make_float2(0.0f, 0.0f);
  w[4] = make_float2(0.0f, b.y*vf);
  w[5] = make_float2(b.z*vf, b.w*vf);
  w[6] = make_float2(c.x*vf, 0.0f);
  w[7] = make_float2(0.0f, 0.0f);
  w[8] = make_float2(0.0f, 0.0f);
  w[9] = make_float2(0.0f, 0.0f);
  int cc[4] = {__float_as_int(dd.x), __float_as_int(dd.y),
               __float_as_int(dd.z), __float_as_int(dd.w)};
  #pragma unroll
  for (int k = 0; k < 4; ++k) {
    if (cc[k] >= 0) {
      uint32_t p = atomicAdd(&cursor[cc[k]], 1u);
      entry[p] = (uint32_t)i;
    }
  }
}

// ---------------- per-cell finalize: sort entries, write grid ---------------
__global__ __launch_bounds__(256) void k_grid(
    const uint32_t* __restrict__ cellcnt, const uint32_t* __restrict__ cellend,
    const uint32_t* __restrict__ entry, float* __restrict__ out)
{
  int wid = threadIdx.x >> 6;
  int lane = threadIdx.x & 63;
  int cell = blockIdx.x*4 + wid;
  uint32_t cnt = cellcnt[cell];
  uint32_t ofs = cellend[cell] - cnt;     // cursor ended at ofs+cnt
  float* g = out + 6 + (size_t)N_PRIM*20 + (size_t)cell*65;
  if (cnt <= 64u) {
    int v = (lane < (int)cnt) ? (int)entry[ofs + lane] : 0x7FFFFFFF;
    #pragma unroll
    for (int k = 2; k <= 64; k <<= 1) {
      #pragma unroll
      for (int j = k>>1; j > 0; j >>= 1) {
        int p = __shfl_xor(v, j, 64);
        bool up = ((lane & k) == 0);
        bool lower = ((lane & j) == 0);
        int mn = min(v,p), mx = max(v,p);
        v = (up == lower) ? mn : mx;
      }
    }
    g[1+lane] = (lane < (int)cnt) ? (float)v : 0.0f;
    if (lane == 0) g[0] = (float)cnt;
  } else {
    int last = -1;
    for (int s = 0; s < 64; ++s) {
      int best = 0x7FFFFFFF;
      for (uint32_t c = lane; c < cnt; c += 64) {
        int v = (int)entry[ofs + c];
        if (v > last && v < best) best = v;
      }
      #pragma unroll
      for (int o = 32; o > 0; o >>= 1) best = min(best, __shfl_xor(best, o, 64));
      if (lane == 0) g[1+s] = (float)best;
      last = best;
    }
    if (lane == 0) g[0] = 64.0f;
  }
}

// ---------------------------------------------------------------------------
extern "C" void kernel_launch(void* const* d_in, const int* in_sizes, int n_in,
                              void* d_out, int out_size, void* d_ws, size_t ws_size,
                              hipStream_t stream)
{
  const float* centers   = (const float*)d_in[0];
  const float* scales    = (const float*)d_in[1];
  const float* rotations = (const float*)d_in[2];
  const float* colors    = (const float*)d_in[3];
  const float* opacities = (const float*)d_in[4];
  const float* mvp       = (const float*)d_in[5];
  const float* background= (const float*)d_in[6];
  float* out = (float*)d_out;
  char* ws = (char*)d_ws;
  if (ws_size < WS_NEED) return;

  uint64_t* sortA  = (uint64_t*)(ws + O_SORTA);
  uint64_t* sortB  = (uint64_t*)(ws + O_SORTB);
  float4*   rec    = (float4*)  (ws + O_REC);
  uint32_t* ccnt   = (uint32_t*)(ws + O_CCNT);
  uint32_t* cstat  = (uint32_t*)(ws + O_CSTAT);
  uint32_t* ghist  = (uint32_t*)(ws + O_GHIST);
  uint32_t* status = (uint32_t*)(ws + O_STATUS);
  uint32_t* gbase  = (uint32_t*)(ws + O_GBASE);
  uint32_t* vcnt   = (uint32_t*)(ws + O_VCNT);
  uint32_t* cofs   = (uint32_t*)(ws + O_COFS);
  uint32_t* entry  = (uint32_t*)(ws + O_ENTRY);

  // one memset: ccnt + cells-scan status + ghist + 4 pass-status slices
  hipMemsetAsync(ws + O_CCNT, 0, O_ZEND - O_CCNT, stream);

  k_prep<<<PREP_BLOCKS, 256, 0, stream>>>(centers, scales, rotations, colors,
                                          opacities, mvp, sortA, rec, ccnt, vcnt);

  // cell-count scan (single-pass lookback) + header fold-in
  k_scan1<<<NCELLS/256, 256, 0, stream>>>(ccnt, cofs, cstat, vcnt, background, out);

  // all-pass global digit histogram + scan
  k_ghist<<<NP2/4096, 256, 0, stream>>>(sortA, ghist);
  k_gscan<<<1, 256, 0, stream>>>(ghist, gbase);

  // 4-pass onesweep radix on bits 20..51
  uint64_t *kin = sortA, *kout = sortB;
  const int shifts[4] = {20, 28, 36, 44};
  for (int pass = 0; pass < 4; ++pass) {
    k_scatter<<<SB, 256, 0, stream>>>(kin, kout, gbase + pass*256,
                                      status + (size_t)pass*256*SB, shifts[pass]);
    uint64_t* tmp = kin; kin = kout; kout = tmp;
  }
  // 4 passes: sorted array back in sortA (== kin)

  k_result<<<(N_PRIM+255)/256, 256, 0, stream>>>(kin, rec, cofs, entry, out);
  k_grid  <<<NCELLS/4, 256, 0, stream>>>(ccnt, cofs, entry, out);
}

// Round 8
// 479.877 us; speedup vs baseline: 12.3761x; 12.3761x over previous
//
#include <hip/hip_runtime.h>
#include <stdint.h>

#pragma clang fp contract(off)

#define N_PRIM   1000000
#define NPAIRS   (N_PRIM/2)               // 500000
#define PREP_BLOCKS ((NPAIRS+255)/256)    // 1954
#define GRID_G   512
#define NCELLS   (GRID_G*GRID_G)          // 262144
#define NBUCK    262144                   // skey>>10 < 2^18
#define FOCAL_C  768.0f
#define KEYC     0x358637BDu              // float bits of 1e-6f (min possible key)

// ---------------- workspace layout (bytes) ----------------
#define O_PK     ((size_t)0)                          // N x u64 packed (skey<<20|idx)
#define O_REC    (O_PK   + (size_t)N_PRIM*8)          // 8 MB
#define O_BSLOT  (O_REC  + (size_t)N_PRIM*64)         // 72 MB: N x u32 bucket slots
#define O_CNT    (O_BSLOT+ (size_t)N_PRIM*4)          // 76 MB: [ccnt 1MB | bcnt 1MB] (memset)
#define O_OFS    (O_CNT  + (size_t)(NCELLS+NBUCK)*4)  // 78 MB: [cofs | bofs]
#define O_CUR    (O_OFS  + (size_t)(NCELLS+NBUCK)*4)  // 80 MB: [ccur | bcur]
#define O_BSUM   (O_CUR  + (size_t)(NCELLS+NBUCK)*4)  // 2048 u32
#define O_VCNT   (O_BSUM + 8192)                      // 1954 u32
#define O_VCSLOT (O_VCNT + 8192)                      // 1 u32 (validCount)
#define O_ENTRY  (O_VCSLOT + 256)                     // 4N u32
#define WS_NEED  (O_ENTRY + (size_t)4*N_PRIM*4)       // ~98.3 MB

__device__ __forceinline__ int swz(int q) { return q ^ ((q >> 3) & 7); }

// ---------------------------------------------------------------------------
__global__ __launch_bounds__(256) void k_prep(
    const float* __restrict__ centers, const float* __restrict__ scales,
    const float* __restrict__ rotations, const float* __restrict__ colors,
    const float* __restrict__ opac, const float* __restrict__ mvp,
    uint64_t* __restrict__ pkarr, float4* __restrict__ rec,
    uint32_t* __restrict__ cellcnt, uint32_t* __restrict__ buckcnt,
    uint32_t* __restrict__ vcnt)
{
  __shared__ float4 srec[2048];          // 512 prims * 4 float4 (swizzled)
  __shared__ uint32_t swcnt[4];
  int t = threadIdx.x;
  int pair = blockIdx.x*256 + t;
  int p0 = pair*2;
  bool live = p0 < N_PRIM;               // pairs never straddle N (N even)

  float m0=mvp[0], m1=mvp[1], m2=mvp[2],  m3=mvp[3];
  float m4=mvp[4], m5=mvp[5], m6=mvp[6],  m7=mvp[7];
  float m8=mvp[8], m9=mvp[9], m10=mvp[10],m11=mvp[11];

  bool valid0=false, valid1=false;
  uint64_t pk0 = ~0ULL, pk1 = ~0ULL;

  if (live) {
    const float2* cp = (const float2*)(centers + (size_t)pair*6);
    float2 ca = cp[0], cb = cp[1], cc = cp[2];
    const float2* sp = (const float2*)(scales + (size_t)pair*6);
    float2 sa = sp[0], sb2 = sp[1], sc2 = sp[2];
    const float4* rp = (const float4*)rotations;
    float4 q0 = rp[p0], q1 = rp[p0+1];
    const float2* colp = (const float2*)(colors + (size_t)pair*6);
    float2 ka = colp[0], kb = colp[1], kc = colp[2];
    float2 o2 = ((const float2*)opac)[pair];

    auto doPrim = [&](int i, float c0, float c1, float c2,
                      float s0, float s1, float s2,
                      float qw, float qx, float qy, float qz,
                      float col0, float col1, float col2, float op,
                      uint64_t& pk, bool& validf, int lidx) {
      float n0 = fmaf(m2,  c2, fmaf(m1, c1, m0*c0)) + m3;
      float n1 = fmaf(m6,  c2, fmaf(m5, c1, m4*c0)) + m7;
      float n2 = fmaf(m10, c2, fmaf(m9, c1, m8*c0)) + m11;
      bool valid = n2 > 0.0f;
      validf = valid;
      float cx = (n0 + 1.0f)*0.5f;
      float cy = (n1 + 1.0f)*0.5f;
      if (valid) {
        // exact float bits of clip(z,1e-6); span < 2^28 above KEYC since z < 4.0
        uint32_t skey = __float_as_uint(fmaxf(n2, 1e-6f)) - KEYC;
        pk = ((uint64_t)skey << 20) | (uint32_t)i;
        atomicAdd(&buckcnt[skey >> 10], 1u);
      }

      float nrm = sqrtf(qw*qw + qx*qx + qy*qy + qz*qz);
      nrm = fmaxf(nrm, 1e-12f);
      qw /= nrm; qx /= nrm; qy /= nrm; qz /= nrm;
      float R00 = 1.0f - 2.0f*(qy*qy + qz*qz);
      float R01 = 2.0f*(qx*qy - qz*qw);
      float R02 = 2.0f*(qx*qz + qy*qw);
      float R10 = 2.0f*(qx*qy + qz*qw);
      float R11 = 1.0f - 2.0f*(qx*qx + qz*qz);
      float R12 = 2.0f*(qy*qz - qx*qw);
      float R20 = 2.0f*(qx*qz - qy*qw);
      float R21 = 2.0f*(qy*qz + qx*qw);
      float R22 = 1.0f - 2.0f*(qx*qx + qy*qy);
      s0 = fmaxf(s0, 1e-9f); s1 = fmaxf(s1, 1e-9f); s2 = fmaxf(s2, 1e-9f);
      float L00=R00*s0, L01=R01*s1, L02=R02*s2;
      float L10=R10*s0, L11=R11*s1, L12=R12*s2;
      float L20=R20*s0, L21=R21*s1, L22=R22*s2;
      float cv00 = fmaf(L02,L02, fmaf(L01,L01, L00*L00));
      float cv01 = fmaf(L02,L12, fmaf(L01,L11, L00*L10));
      float cv02 = fmaf(L02,L22, fmaf(L01,L21, L00*L20));
      float cv11 = fmaf(L12,L12, fmaf(L11,L11, L10*L10));
      float cv12 = fmaf(L12,L22, fmaf(L11,L21, L10*L20));
      float cv22 = fmaf(L22,L22, fmaf(L21,L21, L20*L20));
      float T00 = fmaf(m2,cv02, fmaf(m1,cv01, m0*cv00));
      float T01 = fmaf(m2,cv12, fmaf(m1,cv11, m0*cv01));
      float T02 = fmaf(m2,cv22, fmaf(m1,cv12, m0*cv02));
      float T10 = fmaf(m6,cv02, fmaf(m5,cv01, m4*cv00));
      float T11 = fmaf(m6,cv12, fmaf(m5,cv11, m4*cv01));
      float T12 = fmaf(m6,cv22, fmaf(m5,cv12, m4*cv02));
      float cc00 = fmaf(T02,m2, fmaf(T01,m1, T00*m0));
      float cc01 = fmaf(T02,m6, fmaf(T01,m5, T00*m4));
      float cc11 = fmaf(T12,m6, fmaf(T11,m5, T10*m4));
      float zc  = fmaxf(n2, 1e-6f);
      float scv = FOCAL_C / zc;
      float sc22 = scv*scv;
      float c00 = cc00*sc22, c01 = cc01*sc22, c11 = cc11*sc22;

      float rx = (3.0f * sqrtf(fmaxf(c00, 0.0f))) / 512.0f;
      float ry = (3.0f * sqrtf(fmaxf(c11, 0.0f))) / 512.0f;
      int x0 = (int)floorf((cx - rx) * 512.0f);
      int x1 = (int)floorf((cx + rx) * 512.0f);
      int y0 = (int)floorf((cy - ry) * 512.0f);
      int y1 = (int)floorf((cy + ry) * 512.0f);
      int cl[4];
      #pragma unroll
      for (int ky = 0; ky < 2; ++ky) {
        int yy = y0 + ky;
        bool vy = (yy <= y1) && (yy >= 0) && (yy < GRID_G);
        #pragma unroll
        for (int kx = 0; kx < 2; ++kx) {
          int xx = x0 + kx;
          bool vx = (xx <= x1) && (xx >= 0) && (xx < GRID_G);
          int cell = (valid && vy && vx) ? (yy*GRID_G + xx) : -1;
          cl[ky*2+kx] = cell;
          if (cell >= 0) atomicAdd(&cellcnt[cell], 1u);
        }
      }
      float opv = fminf(fmaxf(op, 0.0f), 1.0f);
      float vf = valid ? 1.0f : 0.0f;
      int lb = lidx*4;
      srec[swz(lb+0)] = make_float4(cx, cy, c00, c01);
      srec[swz(lb+1)] = make_float4(c11, col0, col1, col2);
      srec[swz(lb+2)] = make_float4(opv, vf, 0.0f, 0.0f);
      srec[swz(lb+3)] = make_float4(__int_as_float(cl[0]), __int_as_float(cl[1]),
                                    __int_as_float(cl[2]), __int_as_float(cl[3]));
    };

    doPrim(p0,   ca.x, ca.y, cb.x, sa.x, sa.y, sb2.x,
           q0.x, q0.y, q0.z, q0.w, ka.x, ka.y, kb.x, o2.x, pk0, valid0, 2*t);
    doPrim(p0+1, cb.y, cc.x, cc.y, sb2.y, sc2.x, sc2.y,
           q1.x, q1.y, q1.z, q1.w, kb.y, kc.x, kc.y, o2.y, pk1, valid1, 2*t+1);

    ((ulonglong2*)pkarr)[pair] = make_ulonglong2(pk0, pk1);
  }

  unsigned long long b0 = __ballot(live && valid0);
  unsigned long long b1 = __ballot(live && valid1);
  if ((t & 63) == 0) swcnt[t >> 6] = (uint32_t)(__popcll(b0) + __popcll(b1));
  __syncthreads();
  if (t == 0) vcnt[blockIdx.x] = swcnt[0]+swcnt[1]+swcnt[2]+swcnt[3];

  // coalesced rec writeout
  size_t gbase2 = (size_t)blockIdx.x*2048;
  for (int q = t; q < 2048; q += 256) {
    size_t gi = gbase2 + q;
    if (gi < (size_t)N_PRIM*4) rec[gi] = srec[swz(q)];
  }
}

// ---------------- scans over concatenated [ccnt | bcnt] (2048 blocks) -------
__global__ void k_scanA(const uint32_t* __restrict__ cnt, uint32_t* __restrict__ ofs,
                        uint32_t* __restrict__ bsum)
{
  __shared__ uint32_t s[256];
  int t = threadIdx.x;
  int i = blockIdx.x*256 + t;
  uint32_t v = cnt[i];
  s[t] = v; __syncthreads();
  for (int o = 1; o < 256; o <<= 1) {
    uint32_t u = (t >= o) ? s[t-o] : 0u; __syncthreads();
    s[t] += u; __syncthreads();
  }
  ofs[i] = s[t] - v;
  if (t == 255) bsum[blockIdx.x] = s[t];
}

// partial = sum(bsum[0..bid)); bucket half (bid>=1024) is rebased to 0 by
// subtracting T = sum(bsum[0..1024)). Mirrors into cursor. Block 0 writes
// header + validCount slot.
__global__ void k_scanBC(uint32_t* __restrict__ ofs, const uint32_t* __restrict__ bsum,
                         uint32_t* __restrict__ cursor,
                         const uint32_t* __restrict__ vcnt,
                         const float* __restrict__ bg, float* __restrict__ out,
                         uint32_t* __restrict__ vcslot)
{
  __shared__ uint64_t s8[256];
  __shared__ uint32_t s[256];
  int t = threadIdx.x;
  int bid = blockIdx.x;
  uint64_t acc = 0;   // low: sum i<bid ; high: sum i<1024
  for (int i = t; i < 2048; i += 256) {
    uint32_t v = bsum[i];
    uint64_t add = 0;
    if (i < bid)  add += v;
    if (i < 1024) add += ((uint64_t)v << 32);
    acc += add;
  }
  s8[t] = acc; __syncthreads();
  #pragma unroll
  for (int o = 128; o > 0; o >>= 1) { if (t < o) s8[t] += s8[t+o]; __syncthreads(); }
  uint32_t partial = (uint32_t)s8[0];
  uint32_t T = (uint32_t)(s8[0] >> 32);
  int i = bid*256 + t;
  uint32_t v = ofs[i] + partial - (bid >= 1024 ? T : 0u);
  ofs[i] = v;
  cursor[i] = v;

  if (bid == 0) {   // header fold-in
    __syncthreads();
    uint32_t a2 = 0;
    for (int i2 = t; i2 < PREP_BLOCKS; i2 += 256) a2 += vcnt[i2];
    s[t] = a2; __syncthreads();
    #pragma unroll
    for (int o = 128; o > 0; o >>= 1) { if (t < o) s[t] += s[t+o]; __syncthreads(); }
    if (t == 0) {
      uint32_t vc = s[0];
      out[0] = (float)vc;
      out[1] = 512.0f;
      out[2] = 64.0f;
      out[3] = bg[0]; out[4] = bg[1]; out[5] = bg[2];
      *vcslot = vc;
    }
  }
}

// ---------------- bucket scatter (valid prims only) -------------------------
__global__ __launch_bounds__(256) void k_scatter2(
    const uint64_t* __restrict__ pkarr, uint32_t* __restrict__ bcur,
    uint32_t* __restrict__ bslot)
{
  int i = blockIdx.x*256 + threadIdx.x;
  if (i >= N_PRIM) return;
  uint64_t pk = pkarr[i];
  if (pk == ~0ULL) return;                 // invalid prim
  uint32_t b = (uint32_t)(pk >> 30);       // skey>>10
  uint32_t item = (uint32_t)pk & 0x3FFFFFFFu;  // (skey&1023)<<20 | idx
  uint32_t p = atomicAdd(&bcur[b], 1u);    // absolute slot (mirror of scan)
  bslot[p] = item;
}

// ---- per-bucket exact sort (u32 order == (key,idx) lexicographic) + fused
// ---- result-row write + cell entry emit. One wave per bucket.
__global__ __launch_bounds__(256) void k_bsort(
    const uint32_t* __restrict__ bcnt, const uint32_t* __restrict__ bofs,
    const uint32_t* __restrict__ bslot, const float4* __restrict__ rec,
    uint32_t* __restrict__ ccur, uint32_t* __restrict__ entry,
    float* __restrict__ out)
{
  __shared__ uint32_t stg[4][1024];
  int w = threadIdx.x >> 6, lane = threadIdx.x & 63;
  int b = blockIdx.x*4 + w;
  uint32_t n = bcnt[b];
  if (n == 0) return;
  uint32_t start = bofs[b];
  bool fits = (n <= 1024u);
  if (fits) {
    for (uint32_t e = lane; e < n; e += 64) stg[w][e] = bslot[start + e];
  }
  // wave-internal LDS ordering: same-wave ds ops complete in program order.
  for (uint32_t e = lane; e < n; e += 64) {
    uint32_t it = fits ? stg[w][e] : bslot[start + e];
    uint32_t rank = 0;
    if (fits) {
      for (uint32_t j = 0; j < n; ++j) rank += (stg[w][j] < it);
    } else {
      for (uint32_t j = 0; j < n; ++j) rank += (bslot[start + j] < it);
    }
    uint32_t pos = start + rank;
    int idx = (int)(it & 0xFFFFFu);
    float4 a  = rec[(size_t)idx*4],   bq = rec[(size_t)idx*4+1];
    float4 c  = rec[(size_t)idx*4+2], dd = rec[(size_t)idx*4+3];
    // vf == 1 for all bucketed prims (valid only): values written verbatim
    float2* wp = (float2*)(out + 6 + (size_t)pos*20);
    wp[0] = make_float2(5.0f, a.x);
    wp[1] = make_float2(a.y, a.z);
    wp[2] = make_float2(a.w, bq.x);
    wp[3] = make_float2(0.0f, 0.0f);
    wp[4] = make_float2(0.0f, bq.y);
    wp[5] = make_float2(bq.z, bq.w);
    wp[6] = make_float2(c.x, 0.0f);
    wp[7] = make_float2(0.0f, 0.0f);
    wp[8] = make_float2(0.0f, 0.0f);
    wp[9] = make_float2(0.0f, 0.0f);
    int cc[4] = {__float_as_int(dd.x), __float_as_int(dd.y),
                 __float_as_int(dd.z), __float_as_int(dd.w)};
    #pragma unroll
    for (int k = 0; k < 4; ++k) {
      if (cc[k] >= 0) {
        uint32_t p = atomicAdd(&ccur[cc[k]], 1u);
        entry[p] = pos;
      }
    }
  }
}

// ---------------- zero rows for invalid tail [vc, N) ------------------------
__global__ void k_rowzero(const uint32_t* __restrict__ vcslot, float* __restrict__ out)
{
  uint32_t vc = *vcslot;
  uint32_t i = blockIdx.x*256 + threadIdx.x;
  if (i >= (uint32_t)N_PRIM || i < vc) return;
  float2* wp = (float2*)(out + 6 + (size_t)i*20);
  #pragma unroll
  for (int q = 0; q < 10; ++q) wp[q] = make_float2(0.0f, 0.0f);
}

// ---------------- per-cell finalize: sort entries, write grid ---------------
__global__ __launch_bounds__(256) void k_grid(
    const uint32_t* __restrict__ cellcnt, const uint32_t* __restrict__ cellofs,
    const uint32_t* __restrict__ entry, float* __restrict__ out)
{
  int wid = threadIdx.x >> 6;
  int lane = threadIdx.x & 63;
  int cell = blockIdx.x*4 + wid;
  uint32_t cnt = cellcnt[cell];
  uint32_t ofs = cellofs[cell];
  float* g = out + 6 + (size_t)N_PRIM*20 + (size_t)cell*65;
  if (cnt <= 64u) {
    int v = (lane < (int)cnt) ? (int)entry[ofs + lane] : 0x7FFFFFFF;
    #pragma unroll
    for (int k = 2; k <= 64; k <<= 1) {
      #pragma unroll
      for (int j = k>>1; j > 0; j >>= 1) {
        int p = __shfl_xor(v, j, 64);
        bool up = ((lane & k) == 0);
        bool lower = ((lane & j) == 0);
        int mn = min(v,p), mx = max(v,p);
        v = (up == lower) ? mn : mx;
      }
    }
    g[1+lane] = (lane < (int)cnt) ? (float)v : 0.0f;
    if (lane == 0) g[0] = (float)cnt;
  } else {
    int last = -1;
    for (int s = 0; s < 64; ++s) {
      int best = 0x7FFFFFFF;
      for (uint32_t c = lane; c < cnt; c += 64) {
        int v = (int)entry[ofs + c];
        if (v > last && v < best) best = v;
      }
      #pragma unroll
      for (int o = 32; o > 0; o >>= 1) best = min(best, __shfl_xor(best, o, 64));
      if (lane == 0) g[1+s] = (float)best;
      last = best;
    }
    if (lane == 0) g[0] = 64.0f;
  }
}

// ---------------------------------------------------------------------------
extern "C" void kernel_launch(void* const* d_in, const int* in_sizes, int n_in,
                              void* d_out, int out_size, void* d_ws, size_t ws_size,
                              hipStream_t stream)
{
  const float* centers   = (const float*)d_in[0];
  const float* scales    = (const float*)d_in[1];
  const float* rotations = (const float*)d_in[2];
  const float* colors    = (const float*)d_in[3];
  const float* opacities = (const float*)d_in[4];
  const float* mvp       = (const float*)d_in[5];
  const float* background= (const float*)d_in[6];
  float* out = (float*)d_out;
  char* ws = (char*)d_ws;
  if (ws_size < WS_NEED) return;

  uint64_t* pkarr  = (uint64_t*)(ws + O_PK);
  float4*   rec    = (float4*)  (ws + O_REC);
  uint32_t* bslot  = (uint32_t*)(ws + O_BSLOT);
  uint32_t* ccnt   = (uint32_t*)(ws + O_CNT);                    // [0,NCELLS)
  uint32_t* bcnt   = ccnt + NCELLS;                              // [0,NBUCK)
  uint32_t* cofs   = (uint32_t*)(ws + O_OFS);
  uint32_t* bofs   = cofs + NCELLS;
  uint32_t* ccur   = (uint32_t*)(ws + O_CUR);
  uint32_t* bcur   = ccur + NCELLS;
  uint32_t* bsum   = (uint32_t*)(ws + O_BSUM);
  uint32_t* vcnt   = (uint32_t*)(ws + O_VCNT);
  uint32_t* vcslot = (uint32_t*)(ws + O_VCSLOT);
  uint32_t* entry  = (uint32_t*)(ws + O_ENTRY);

  // zero cell + bucket counts (contiguous 2 MB)
  hipMemsetAsync(ws + O_CNT, 0, (size_t)(NCELLS+NBUCK)*4, stream);

  k_prep<<<PREP_BLOCKS, 256, 0, stream>>>(centers, scales, rotations, colors,
                                          opacities, mvp, pkarr, rec,
                                          ccnt, bcnt, vcnt);

  // one scan pair over concatenated [ccnt|bcnt]; bucket half rebased to 0
  k_scanA <<<(NCELLS+NBUCK)/256, 256, 0, stream>>>(ccnt, cofs, bsum);
  k_scanBC<<<(NCELLS+NBUCK)/256, 256, 0, stream>>>(cofs, bsum, ccur, vcnt,
                                                   background, out, vcslot);

  k_scatter2<<<(N_PRIM+255)/256, 256, 0, stream>>>(pkarr, bcur, bslot);

  k_bsort<<<NBUCK/4, 256, 0, stream>>>(bcnt, bofs, bslot, rec, ccur, entry, out);

  k_rowzero<<<(N_PRIM+255)/256, 256, 0, stream>>>(vcslot, out);

  k_grid<<<NCELLS/4, 256, 0, stream>>>(ccnt, cofs, entry, out);
}

// Round 10
// 464.665 us; speedup vs baseline: 12.7813x; 1.0327x over previous
//
#include <hip/hip_runtime.h>
#include <stdint.h>

#pragma clang fp contract(off)

#define N_PRIM   1000000
#define NPAIRS   (N_PRIM/2)               // 500000
#define PREP_BLOCKS ((NPAIRS+255)/256)    // 1954
#define GRID_G   512
#define NCELLS   (GRID_G*GRID_G)          // 262144
#define NBUCK    262144                   // skey>>10 < 2^18
#define FOCAL_C  768.0f
#define KEYC     0x358637BDu              // float bits of 1e-6f (min possible key)

// ---------------- workspace layout (bytes) ----------------
#define O_PK     ((size_t)0)                          // N x u64 packed (skey<<20|idx)
#define O_REC    (O_PK   + (size_t)N_PRIM*8)          // 8 MB
#define O_BSLOT  (O_REC  + (size_t)N_PRIM*48)         // 56 MB
#define O_CNT    (O_BSLOT+ (size_t)N_PRIM*4)          // 60 MB: [ccnt | bcnt] (memset)
#define O_OFS    (O_CNT  + (size_t)(NCELLS+NBUCK)*4)  // [cofs | bofs]
#define O_CUR    (O_OFS  + (size_t)(NCELLS+NBUCK)*4)  // [ccur | bcur]
#define O_BSUM   (O_CUR  + (size_t)(NCELLS+NBUCK)*4)  // 2048 u32
#define O_VCNT   (O_BSUM + 8192)                      // 1954 u32
#define O_VCSLOT (O_VCNT + 8192)                      // 1 u32
#define O_ENTRY  (O_VCSLOT + 256)                     // 4N u32
#define WS_NEED  (O_ENTRY + (size_t)4*N_PRIM*4)       // ~82.3 MB

__device__ __forceinline__ int swz(int q) { return q ^ ((q >> 3) & 7); }

// ---------------------------------------------------------------------------
__global__ __launch_bounds__(256) void k_prep(
    const float* __restrict__ centers, const float* __restrict__ scales,
    const float* __restrict__ rotations, const float* __restrict__ colors,
    const float* __restrict__ opac, const float* __restrict__ mvp,
    uint64_t* __restrict__ pkarr, float4* __restrict__ rec,
    uint32_t* __restrict__ cellcnt, uint32_t* __restrict__ buckcnt,
    uint32_t* __restrict__ vcnt)
{
  __shared__ float4 srec[1536];          // 512 prims * 3 float4 (swizzled)
  __shared__ uint32_t swcnt[4];
  int t = threadIdx.x;
  int pair = blockIdx.x*256 + t;
  int p0 = pair*2;
  bool live = pair < NPAIRS;

  float m0=mvp[0], m1=mvp[1], m2=mvp[2],  m3=mvp[3];
  float m4=mvp[4], m5=mvp[5], m6=mvp[6],  m7=mvp[7];
  float m8=mvp[8], m9=mvp[9], m10=mvp[10],m11=mvp[11];

  bool valid0=false, valid1=false;
  uint64_t pk0 = ~0ULL, pk1 = ~0ULL;

  if (live) {
    const float2* cp = (const float2*)(centers + (size_t)pair*6);
    float2 ca = cp[0], cb = cp[1], cc = cp[2];
    const float2* sp = (const float2*)(scales + (size_t)pair*6);
    float2 sa = sp[0], sb2 = sp[1], sc2 = sp[2];
    const float4* rp = (const float4*)rotations;
    float4 q0 = rp[p0], q1 = rp[p0+1];
    const float2* colp = (const float2*)(colors + (size_t)pair*6);
    float2 ka = colp[0], kb = colp[1], kc = colp[2];
    float2 o2 = ((const float2*)opac)[pair];

    auto doPrim = [&](int i, float c0, float c1, float c2,
                      float s0, float s1, float s2,
                      float qw, float qx, float qy, float qz,
                      float col0, float col1, float col2, float op,
                      uint64_t& pk, bool& validf, int lidx) {
      float n0 = fmaf(m2,  c2, fmaf(m1, c1, m0*c0)) + m3;
      float n1 = fmaf(m6,  c2, fmaf(m5, c1, m4*c0)) + m7;
      float n2 = fmaf(m10, c2, fmaf(m9, c1, m8*c0)) + m11;
      bool valid = n2 > 0.0f;
      validf = valid;
      float cx = (n0 + 1.0f)*0.5f;
      float cy = (n1 + 1.0f)*0.5f;
      if (valid) {
        // exact float bits of clip(z,1e-6); span < 2^28 since z < 4.0
        uint32_t skey = __float_as_uint(fmaxf(n2, 1e-6f)) - KEYC;
        pk = ((uint64_t)skey << 20) | (uint32_t)i;
        atomicAdd(&buckcnt[skey >> 10], 1u);
      }
      float nrm = sqrtf(qw*qw + qx*qx + qy*qy + qz*qz);
      nrm = fmaxf(nrm, 1e-12f);
      qw /= nrm; qx /= nrm; qy /= nrm; qz /= nrm;
      float R00 = 1.0f - 2.0f*(qy*qy + qz*qz);
      float R01 = 2.0f*(qx*qy - qz*qw);
      float R02 = 2.0f*(qx*qz + qy*qw);
      float R10 = 2.0f*(qx*qy + qz*qw);
      float R11 = 1.0f - 2.0f*(qx*qx + qz*qz);
      float R12 = 2.0f*(qy*qz - qx*qw);
      float R20 = 2.0f*(qx*qz - qy*qw);
      float R21 = 2.0f*(qy*qz + qx*qw);
      float R22 = 1.0f - 2.0f*(qx*qx + qy*qy);
      s0 = fmaxf(s0, 1e-9f); s1 = fmaxf(s1, 1e-9f); s2 = fmaxf(s2, 1e-9f);
      float L00=R00*s0, L01=R01*s1, L02=R02*s2;
      float L10=R10*s0, L11=R11*s1, L12=R12*s2;
      float L20=R20*s0, L21=R21*s1, L22=R22*s2;
      float cv00 = fmaf(L02,L02, fmaf(L01,L01, L00*L00));
      float cv01 = fmaf(L02,L12, fmaf(L01,L11, L00*L10));
      float cv02 = fmaf(L02,L22, fmaf(L01,L21, L00*L20));
      float cv11 = fmaf(L12,L12, fmaf(L11,L11, L10*L10));
      float cv12 = fmaf(L12,L22, fmaf(L11,L21, L10*L20));
      float cv22 = fmaf(L22,L22, fmaf(L21,L21, L20*L20));
      float T00 = fmaf(m2,cv02, fmaf(m1,cv01, m0*cv00));
      float T01 = fmaf(m2,cv12, fmaf(m1,cv11, m0*cv01));
      float T02 = fmaf(m2,cv22, fmaf(m1,cv12, m0*cv02));
      float T10 = fmaf(m6,cv02, fmaf(m5,cv01, m4*cv00));
      float T11 = fmaf(m6,cv12, fmaf(m5,cv11, m4*cv01));
      float T12 = fmaf(m6,cv22, fmaf(m5,cv12, m4*cv02));
      float cc00 = fmaf(T02,m2, fmaf(T01,m1, T00*m0));
      float cc01 = fmaf(T02,m6, fmaf(T01,m5, T00*m4));
      float cc11 = fmaf(T12,m6, fmaf(T11,m5, T10*m4));
      float zc  = fmaxf(n2, 1e-6f);
      float scv = FOCAL_C / zc;
      float sc22 = scv*scv;
      float c00 = cc00*sc22, c01 = cc01*sc22, c11 = cc11*sc22;

      float rx = (3.0f * sqrtf(fmaxf(c00, 0.0f))) / 512.0f;
      float ry = (3.0f * sqrtf(fmaxf(c11, 0.0f))) / 512.0f;
      int x0 = (int)floorf((cx - rx) * 512.0f);
      int x1 = (int)floorf((cx + rx) * 512.0f);
      int y0 = (int)floorf((cy - ry) * 512.0f);
      int y1 = (int)floorf((cy + ry) * 512.0f);
      #pragma unroll
      for (int ky = 0; ky < 2; ++ky) {
        int yy = y0 + ky;
        bool vy = (yy <= y1) && (yy >= 0) && (yy < GRID_G);
        #pragma unroll
        for (int kx = 0; kx < 2; ++kx) {
          int xx = x0 + kx;
          bool vx = (xx <= x1) && (xx >= 0) && (xx < GRID_G);
          if (valid && vy && vx) atomicAdd(&cellcnt[yy*GRID_G + xx], 1u);
        }
      }
      float opv = fminf(fmaxf(op, 0.0f), 1.0f);
      float vf = valid ? 1.0f : 0.0f;
      int lb = lidx*3;
      srec[swz(lb+0)] = make_float4(cx, cy, c00, c01);
      srec[swz(lb+1)] = make_float4(c11, col0, col1, col2);
      srec[swz(lb+2)] = make_float4(opv, vf, 0.0f, 0.0f);
    };

    doPrim(p0,   ca.x, ca.y, cb.x, sa.x, sa.y, sb2.x,
           q0.x, q0.y, q0.z, q0.w, ka.x, ka.y, kb.x, o2.x, pk0, valid0, 2*t);
    doPrim(p0+1, cb.y, cc.x, cc.y, sb2.y, sc2.x, sc2.y,
           q1.x, q1.y, q1.z, q1.w, kb.y, kc.x, kc.y, o2.y, pk1, valid1, 2*t+1);

    ((ulonglong2*)pkarr)[pair] = make_ulonglong2(pk0, pk1);
  }

  unsigned long long b0 = __ballot(live && valid0);
  unsigned long long b1 = __ballot(live && valid1);
  if ((t & 63) == 0) swcnt[t >> 6] = (uint32_t)(__popcll(b0) + __popcll(b1));
  __syncthreads();
  if (t == 0) vcnt[blockIdx.x] = swcnt[0]+swcnt[1]+swcnt[2]+swcnt[3];

  // coalesced rec writeout (512 prims * 3 float4 per block)
  size_t gbase2 = (size_t)blockIdx.x*1536;
  for (int q = t; q < 1536; q += 256) {
    size_t gi = gbase2 + q;
    if (gi < (size_t)N_PRIM*3) rec[gi] = srec[swz(q)];
  }
}

// ---------------- scans over concatenated [ccnt | bcnt] (2048 blocks) -------
__global__ void k_scanA(const uint32_t* __restrict__ cnt, uint32_t* __restrict__ ofs,
                        uint32_t* __restrict__ bsum)
{
  __shared__ uint32_t s[256];
  int t = threadIdx.x;
  int i = blockIdx.x*256 + t;
  uint32_t v = cnt[i];
  s[t] = v; __syncthreads();
  for (int o = 1; o < 256; o <<= 1) {
    uint32_t u = (t >= o) ? s[t-o] : 0u; __syncthreads();
    s[t] += u; __syncthreads();
  }
  ofs[i] = s[t] - v;
  if (t == 255) bsum[blockIdx.x] = s[t];
}

// partial = sum(bsum[0..bid)); bucket half (bid>=1024) rebased to 0 by
// subtracting T = sum(bsum[0..1024)). Mirrors into cursor. Block 0 writes
// header + validCount slot.
__global__ void k_scanBC(uint32_t* __restrict__ ofs, const uint32_t* __restrict__ bsum,
                         uint32_t* __restrict__ cursor,
                         const uint32_t* __restrict__ vcnt,
                         const float* __restrict__ bg, float* __restrict__ out,
                         uint32_t* __restrict__ vcslot)
{
  __shared__ uint64_t s8[256];
  __shared__ uint32_t s[256];
  int t = threadIdx.x;
  int bid = blockIdx.x;
  uint64_t acc = 0;   // low: sum i<bid ; high: sum i<1024
  for (int i = t; i < 2048; i += 256) {
    uint32_t v = bsum[i];
    if (i < bid)  acc += v;
    if (i < 1024) acc += ((uint64_t)v << 32);
  }
  s8[t] = acc; __syncthreads();
  #pragma unroll
  for (int o = 128; o > 0; o >>= 1) { if (t < o) s8[t] += s8[t+o]; __syncthreads(); }
  uint32_t partial = (uint32_t)s8[0];
  uint32_t T = (uint32_t)(s8[0] >> 32);
  int i = bid*256 + t;
  uint32_t v = ofs[i] + partial - (bid >= 1024 ? T : 0u);
  ofs[i] = v;
  cursor[i] = v;

  if (bid == 0) {   // header fold-in
    __syncthreads();
    uint32_t a2 = 0;
    for (int i2 = t; i2 < PREP_BLOCKS; i2 += 256) a2 += vcnt[i2];
    s[t] = a2; __syncthreads();
    #pragma unroll
    for (int o = 128; o > 0; o >>= 1) { if (t < o) s[t] += s[t+o]; __syncthreads(); }
    if (t == 0) {
      uint32_t vc = s[0];
      out[0] = (float)vc;
      out[1] = 512.0f;
      out[2] = 64.0f;
      out[3] = bg[0]; out[4] = bg[1]; out[5] = bg[2];
      *vcslot = vc;
    }
  }
}

// ------- bucket scatter (valid prims) + zero rows for invalid tail ----------
__global__ __launch_bounds__(256) void k_scatter2(
    const uint64_t* __restrict__ pkarr, uint32_t* __restrict__ bcur,
    uint32_t* __restrict__ bslot, const uint32_t* __restrict__ vcslot,
    float* __restrict__ out)
{
  int i = blockIdx.x*256 + threadIdx.x;
  if (i >= N_PRIM) return;
  uint64_t pk = pkarr[i];
  if (pk != ~0ULL) {
    uint32_t b = (uint32_t)(pk >> 30);       // skey>>10
    uint32_t item = (uint32_t)pk & 0x3FFFFFFFu;  // (skey&1023)<<20 | idx
    uint32_t p = atomicAdd(&bcur[b], 1u);
    bslot[p] = item;
  }
  uint32_t vc = *vcslot;
  if ((uint32_t)i >= vc) {
    float2* wp = (float2*)(out + 6 + (size_t)i*20);
    #pragma unroll
    for (int q = 0; q < 10; ++q) wp[q] = make_float2(0.0f, 0.0f);
  }
}

// ---- per-bucket exact sort (u32 order == (key,idx) lexicographic) + fused
// ---- result-row write + cell entry emit (cells recomputed bit-identically).
__global__ __launch_bounds__(256) void k_bsort(
    const uint32_t* __restrict__ bcnt, const uint32_t* __restrict__ bofs,
    const uint32_t* __restrict__ bslot, const float4* __restrict__ rec,
    uint32_t* __restrict__ ccur, uint32_t* __restrict__ entry,
    float* __restrict__ out)
{
  __shared__ uint32_t stg[4][1024];
  int w = threadIdx.x >> 6, lane = threadIdx.x & 63;
  int b = blockIdx.x*4 + w;
  uint32_t n = bcnt[b];
  if (n == 0) return;
  uint32_t start = bofs[b];
  bool fits = (n <= 1024u);
  if (fits) {
    for (uint32_t e = lane; e < n; e += 64) stg[w][e] = bslot[start + e];
  }
  for (uint32_t e = lane; e < n; e += 64) {
    uint32_t it = fits ? stg[w][e] : bslot[start + e];
    uint32_t rank = 0;
    if (fits) {
      for (uint32_t j = 0; j < n; ++j) rank += (stg[w][j] < it);
    } else {
      for (uint32_t j = 0; j < n; ++j) rank += (bslot[start + j] < it);
    }
    uint32_t pos = start + rank;
    int idx = (int)(it & 0xFFFFFu);
    float4 a  = rec[(size_t)idx*3],   bq = rec[(size_t)idx*3+1];
    float4 c  = rec[(size_t)idx*3+2];
    // vf == 1 for all bucketed prims: values written verbatim
    float2* wp = (float2*)(out + 6 + (size_t)pos*20);
    wp[0] = make_float2(5.0f, a.x);
    wp[1] = make_float2(a.y, a.z);
    wp[2] = make_float2(a.w, bq.x);
    wp[3] = make_float2(0.0f, 0.0f);
    wp[4] = make_float2(0.0f, bq.y);
    wp[5] = make_float2(bq.z, bq.w);
    wp[6] = make_float2(c.x, 0.0f);
    wp[7] = make_float2(0.0f, 0.0f);
    wp[8] = make_float2(0.0f, 0.0f);
    wp[9] = make_float2(0.0f, 0.0f);
    // recompute cells from stored cx,cy,c00,c11 (bit-identical to k_prep)
    float cx = a.x, cy = a.y, c00 = a.z, c11 = bq.x;
    float rx = (3.0f * sqrtf(fmaxf(c00, 0.0f))) / 512.0f;
    float ry = (3.0f * sqrtf(fmaxf(c11, 0.0f))) / 512.0f;
    int x0 = (int)floorf((cx - rx) * 512.0f);
    int x1 = (int)floorf((cx + rx) * 512.0f);
    int y0 = (int)floorf((cy - ry) * 512.0f);
    int y1 = (int)floorf((cy + ry) * 512.0f);
    #pragma unroll
    for (int ky = 0; ky < 2; ++ky) {
      int yy = y0 + ky;
      bool vy = (yy <= y1) && (yy >= 0) && (yy < GRID_G);
      #pragma unroll
      for (int kx = 0; kx < 2; ++kx) {
        int xx = x0 + kx;
        bool vx = (xx <= x1) && (xx >= 0) && (xx < GRID_G);
        if (vy && vx) {
          uint32_t p = atomicAdd(&ccur[yy*GRID_G + xx], 1u);
          entry[p] = pos;
        }
      }
    }
  }
}

// ---------------- per-cell finalize: sort entries, write grid ---------------
__global__ __launch_bounds__(256) void k_grid(
    const uint32_t* __restrict__ cellcnt, const uint32_t* __restrict__ cellofs,
    const uint32_t* __restrict__ entry, float* __restrict__ out)
{
  int wid = threadIdx.x >> 6;
  int lane = threadIdx.x & 63;
  int cell = blockIdx.x*4 + wid;
  uint32_t cnt = cellcnt[cell];
  uint32_t ofs = cellofs[cell];
  float* g = out + 6 + (size_t)N_PRIM*20 + (size_t)cell*65;
  if (cnt <= 64u) {
    int v = (lane < (int)cnt) ? (int)entry[ofs + lane] : 0x7FFFFFFF;
    #pragma unroll
    for (int k = 2; k <= 64; k <<= 1) {
      #pragma unroll
      for (int j = k>>1; j > 0; j >>= 1) {
        int p = __shfl_xor(v, j, 64);
        bool up = ((lane & k) == 0);
        bool lower = ((lane & j) == 0);
        int mn = min(v,p), mx = max(v,p);
        v = (up == lower) ? mn : mx;
      }
    }
    g[1+lane] = (lane < (int)cnt) ? (float)v : 0.0f;
    if (lane == 0) g[0] = (float)cnt;
  } else {
    int last = -1;
    for (int s = 0; s < 64; ++s) {
      int best = 0x7FFFFFFF;
      for (uint32_t c = lane; c < cnt; c += 64) {
        int v = (int)entry[ofs + c];
        if (v > last && v < best) best = v;
      }
      #pragma unroll
      for (int o = 32; o > 0; o >>= 1) best = min(best, __shfl_xor(best, o, 64));
      if (lane == 0) g[1+s] = (float)best;
      last = best;
    }
    if (lane == 0) g[0] = 64.0f;
  }
}

// ---------------------------------------------------------------------------
extern "C" void kernel_launch(void* const* d_in, const int* in_sizes, int n_in,
                              void* d_out, int out_size, void* d_ws, size_t ws_size,
                              hipStream_t stream)
{
  const float* centers   = (const float*)d_in[0];
  const float* scales    = (const float*)d_in[1];
  const float* rotations = (const float*)d_in[2];
  const float* colors    = (const float*)d_in[3];
  const float* opacities = (const float*)d_in[4];
  const float* mvp       = (const float*)d_in[5];
  const float* background= (const float*)d_in[6];
  float* out = (float*)d_out;
  char* ws = (char*)d_ws;
  if (ws_size < WS_NEED) return;

  uint64_t* pkarr  = (uint64_t*)(ws + O_PK);
  float4*   rec    = (float4*)  (ws + O_REC);
  uint32_t* bslot  = (uint32_t*)(ws + O_BSLOT);
  uint32_t* ccnt   = (uint32_t*)(ws + O_CNT);                    // [0,NCELLS)
  uint32_t* bcnt   = ccnt + NCELLS;                              // [0,NBUCK)
  uint32_t* cofs   = (uint32_t*)(ws + O_OFS);
  uint32_t* bofs   = cofs + NCELLS;
  uint32_t* ccur   = (uint32_t*)(ws + O_CUR);
  uint32_t* bcur   = ccur + NCELLS;
  uint32_t* bsum   = (uint32_t*)(ws + O_BSUM);
  uint32_t* vcnt   = (uint32_t*)(ws + O_VCNT);
  uint32_t* vcslot = (uint32_t*)(ws + O_VCSLOT);
  uint32_t* entry  = (uint32_t*)(ws + O_ENTRY);

  // zero cell + bucket counts (contiguous 2 MB)
  hipMemsetAsync(ws + O_CNT, 0, (size_t)(NCELLS+NBUCK)*4, stream);

  k_prep<<<PREP_BLOCKS, 256, 0, stream>>>(centers, scales, rotations, colors,
                                          opacities, mvp, pkarr, rec,
                                          ccnt, bcnt, vcnt);

  // one scan pair over concatenated [ccnt|bcnt]; bucket half rebased to 0
  k_scanA <<<(NCELLS+NBUCK)/256, 256, 0, stream>>>(ccnt, cofs, bsum);
  k_scanBC<<<(NCELLS+NBUCK)/256, 256, 0, stream>>>(cofs, bsum, ccur, vcnt,
                                                   background, out, vcslot);

  k_scatter2<<<(N_PRIM+255)/256, 256, 0, stream>>>(pkarr, bcur, bslot, vcslot, out);

  k_bsort<<<NBUCK/4, 256, 0, stream>>>(bcnt, bofs, bslot, rec, ccur, entry, out);

  k_grid<<<NCELLS/4, 256, 0, stream>>>(ccnt, cofs, entry, out);
}